// Round 8
// baseline (1189.282 us; speedup 1.0000x reference)
//
#include <hip/hip_runtime.h>
#include <hip/hip_bf16.h>
#include <stdint.h>

#define B_ 2
#define S_ 4096
#define DM 1024
#define H_ 16
#define HD 64
#define M_TOT (B_*S_)   // 8192

typedef unsigned short u16;
typedef short s16x8 __attribute__((ext_vector_type(8)));
typedef short s16x4 __attribute__((ext_vector_type(4)));
typedef float f32x4 __attribute__((ext_vector_type(4)));
typedef uint32_t u32x2 __attribute__((ext_vector_type(2)));

__device__ __forceinline__ u16 f2bf(float f){
  union { float fv; uint32_t u; } x; x.fv = f;
  uint32_t r = (x.u + 0x7fffu + ((x.u >> 16) & 1u)) >> 16;
  return (u16)r;
}

// pack two f32 -> bf16x2 (a -> low 16, b -> high 16)
#if __has_builtin(__builtin_amdgcn_cvt_pk_bf16_f32)
typedef __bf16 bf16x2_t __attribute__((ext_vector_type(2)));
__device__ __forceinline__ uint32_t pkbf(float a, float b){
  union { bf16x2_t v; uint32_t u; } x;
  x.v = __builtin_amdgcn_cvt_pk_bf16_f32(a, b);
  return x.u;
}
#else
__device__ __forceinline__ uint32_t pkbf(float a, float b){
  union { float f; uint32_t u; } xa, xb; xa.f = a; xb.f = b;
  return __builtin_amdgcn_perm(xb.u + 0x8000u, xa.u + 0x8000u, 0x07060302u);
}
#endif

__device__ __forceinline__ void gld_lds16(const void* g, void* l){
  __builtin_amdgcn_global_load_lds((const __attribute__((address_space(1))) void*)g,
                                   (__attribute__((address_space(3))) void*)l, 16, 0, 0);
}

// ------- merged prep: x fp32->bf16 (blocks 0..4095) + W transpose (4096..5119) ----
// The two jobs are independent; one launch lets them overlap instead of
// serializing on the stream.
__global__ __launch_bounds__(256) void k_prep(const float* __restrict__ x, u16* __restrict__ xb,
                                              const float* __restrict__ W0, const float* __restrict__ W1,
                                              const float* __restrict__ W2, const float* __restrict__ W3,
                                              u16* __restrict__ wt){
  __shared__ u16 T[64*66];
  int t = threadIdx.x;
  if (blockIdx.x < 4096){
    size_t i = (size_t)blockIdx.x * 256 + t;
    const float4* p = (const float4*)x + i*2;
    float4 a = p[0], b = p[1];
    union { u16 u[8]; uint4 v; } o;
    o.u[0]=f2bf(a.x); o.u[1]=f2bf(a.y); o.u[2]=f2bf(a.z); o.u[3]=f2bf(a.w);
    o.u[4]=f2bf(b.x); o.u[5]=f2bf(b.y); o.u[6]=f2bf(b.z); o.u[7]=f2bf(b.w);
    ((uint4*)xb)[i] = o.v;
    return;
  }
  int idx = blockIdx.x - 4096;           // 0..1023
  int bx = idx & 15, by = (idx >> 4) & 15, bz = idx >> 8;
  const float* W = bz==0?W0: bz==1?W1: bz==2?W2:W3;
  u16* out = wt + (size_t)bz * DM * DM;
  int n0 = bx*64, k0 = by*64;
  #pragma unroll
  for (int i=0;i<4;i++){
    int id2 = t + i*256;
    int kr = id2 >> 4, n4 = id2 & 15;
    float4 v = *(const float4*)(W + (size_t)(k0+kr)*DM + n0 + n4*4);
    T[(n4*4+0)*66 + kr] = f2bf(v.x);
    T[(n4*4+1)*66 + kr] = f2bf(v.y);
    T[(n4*4+2)*66 + kr] = f2bf(v.z);
    T[(n4*4+3)*66 + kr] = f2bf(v.w);
  }
  __syncthreads();
  #pragma unroll
  for (int i=0;i<2;i++){
    int id2 = t + i*256;
    int n = id2 >> 3, k8 = id2 & 7;
    union { u16 u[8]; uint4 v; } o;
    #pragma unroll
    for (int j=0;j<8;j++) o.u[j] = T[n*66 + k8*8 + j];
    *(uint4*)(out + (size_t)(n0+n)*DM + k0 + k8*8) = o.v;
  }
}

// ---------------- 128x128 MFMA GEMM, A[M,K] bf16 row-major, BT[N,K] bf16 ----
// v4: BK=64, XOR-swizzled LDS, bf16 epilogue staged through LDS for b128
// stores. (Round-7 proven.)
__device__ __forceinline__ void gemm128(const u16* __restrict__ A, const u16* __restrict__ BT,
                                        const float* __restrict__ bias, bool brow, float scale,
                                        u16* __restrict__ outb, float* __restrict__ outf,
                                        int m0, int n0, int ldo){
  __shared__ __align__(16) u16 S[16384];     // As = S[0:8192), Bs = S[8192:16384)
  u16* As = S;
  u16* Bs = S + 8192;
  int t = threadIdx.x;
  int lane = t & 63, w = t >> 6;
  int wm = w & 1, wn = w >> 1;
  int c16 = lane & 15, quad = lane >> 4;
  f32x4 acc[4][4] = {};
  const u16* ap[4]; const u16* bp[4];
  #pragma unroll
  for (int i=0;i<4;i++){
    int c = t + i*256;
    int row = c >> 3, scol = (c & 7) ^ (row & 7);
    ap[i] = A  + (size_t)(m0+row)*DM + scol*8;
    bp[i] = BT + (size_t)(n0+row)*DM + scol*8;
  }
  for (int k0 = 0; k0 < DM; k0 += 64){
    #pragma unroll
    for (int i=0;i<4;i++){
      int c = t + i*256;
      gld_lds16(ap[i] + k0, &As[c*8]);
      gld_lds16(bp[i] + k0, &Bs[c*8]);
    }
    __syncthreads();
    #pragma unroll
    for (int ks=0; ks<2; ks++){
      s16x8 af[4], bfr[4];
      #pragma unroll
      for (int mi=0;mi<4;mi++){
        int row = wm*64 + mi*16 + c16;
        af[mi] = *(const s16x8*)&As[row*64 + (((ks*4 + quad) ^ (row & 7))*8)];
      }
      #pragma unroll
      for (int ni=0;ni<4;ni++){
        int row = wn*64 + ni*16 + c16;
        bfr[ni] = *(const s16x8*)&Bs[row*64 + (((ks*4 + quad) ^ (row & 7))*8)];
      }
      #pragma unroll
      for (int mi=0;mi<4;mi++)
        #pragma unroll
        for (int ni=0;ni<4;ni++)
          acc[mi][ni] = __builtin_amdgcn_mfma_f32_16x16x32_bf16(af[mi], bfr[ni], acc[mi][ni], 0, 0, 0);
    }
    __syncthreads();
  }
  if (outb){
    #pragma unroll
    for (int mi=0;mi<4;mi++){
      #pragma unroll
      for (int ni=0;ni<4;ni++){
        int lc = wn*64 + ni*16 + c16;            // local col 0..127
        float bc = brow ? 0.0f : bias[n0 + lc];
        int chunk = lc >> 3, off = lc & 7;
        #pragma unroll
        for (int r=0;r<4;r++){
          int lrow = wm*64 + mi*16 + quad*4 + r; // local row 0..127
          float bb = brow ? bias[m0 + lrow] : bc;
          float v = (acc[mi][ni][r] + bb) * scale;
          S[lrow*128 + ((chunk ^ (lrow & 7))<<3) + off] = f2bf(v);
        }
      }
    }
    __syncthreads();
    #pragma unroll
    for (int i=0;i<4;i++){
      int row = (t >> 3) + i*32;
      #pragma unroll
      for (int j=0;j<2;j++){
        int ch = (t & 7) + j*8;
        uint4 vv = *(const uint4*)&S[row*128 + ((ch ^ (row & 7))<<3)];
        *(uint4*)(outb + (size_t)(m0+row)*ldo + n0 + ch*8) = vv;
      }
    }
  } else {
    #pragma unroll
    for (int mi=0;mi<4;mi++){
      #pragma unroll
      for (int ni=0;ni<4;ni++){
        int col = n0 + wn*64 + ni*16 + c16;
        float bc = bias[col];
        #pragma unroll
        for (int r=0;r<4;r++){
          int row = m0 + wm*64 + mi*16 + quad*4 + r;
          outf[(size_t)row*ldo + col] = (acc[mi][ni][r] + bc) * scale;
        }
      }
    }
  }
}

#define CL2 0.18033688011112042f   // log2(e)/sqrt(64)

// T1 XCD-aware swizzle (bijective, 512 % 8 == 0).
__device__ __forceinline__ void gemm_swz(int wg, int& m0, int& n0){
  int xcd = wg & 7, loc = wg >> 3;            // loc in [0,64)
  m0 = ((xcd << 3) + (loc >> 3)) * 128;       // M-tile 0..63
  n0 = (loc & 7) * 128;                       // N-tile 0..7
}

// z=0: Q = X*Wq (scaled CL2), z=1: K = X*Wk, z=2: V^T = Wv^T * X^T.
__global__ __launch_bounds__(256) void k_gemm_qkv(const u16* __restrict__ xb, const u16* __restrict__ wt,
                                                  const float* __restrict__ b0, const float* __restrict__ b1,
                                                  const float* __restrict__ b2,
                                                  u16* __restrict__ q, u16* __restrict__ k, u16* __restrict__ vt){
  int z = blockIdx.z;
  int m0, n0;
  gemm_swz(blockIdx.x + (blockIdx.y << 3), m0, n0);
  const u16* Aarg; const u16* Barg; const float* bias; float scale; u16* out;
  int mm, nn, ldo; bool brow;
  if (z == 2){
    Aarg = wt + 2*(size_t)DM*DM; Barg = xb; bias = b2; brow = true;  scale = 1.0f;
    out = vt; mm = n0; nn = m0; ldo = M_TOT;
  } else {
    Aarg = xb; Barg = wt + (size_t)z*DM*DM; bias = z ? b1 : b0; brow = false;
    scale = z ? 1.0f : CL2; out = z ? k : q; mm = m0; nn = n0; ldo = DM;
  }
  gemm128(Aarg, Barg, bias, brow, scale, out, nullptr, mm, nn, ldo);
}

__global__ __launch_bounds__(256) void k_gemm_out(const u16* __restrict__ ab, const u16* __restrict__ wto,
                                                  const float* __restrict__ bias, float* __restrict__ out){
  int m0, n0;
  gemm_swz(blockIdx.x + (blockIdx.y << 3), m0, n0);
  gemm128(ab, wto, bias, false, 1.0f, nullptr, out, m0, n0, DM);
}

// ---------------- flash attention v14: K in REGISTERS, V-only LDS ----------
// Round-7 showed MFMA -33% with zero time delta -> not MFMA-bound. Cycle
// model: LDS pipe was ~80% of wall (K-reads 64KB + V-reads 64KB + staging
// 32KB per block-tile at 128 B/cyc, x2 blocks/CU). Fix: each wave reads its
// own 4x16 K-rows direct from global (L1/L2-hot, 4x reuse within ~1us) into
// 8 persistent VGPR frags, prefetched one tile ahead (issued right after
// last kf use). LDS traffic halves; K staging deleted. vmcnt ledger per
// iter: [V(t):2, K(t):8, V(t+1):2] -> manual vmcnt(2) drains V(t)+K(t),
// keeps V(t+1) in flight. LDS 38912 B. launch_bounds(512,4) pins VGPR<=128
// so 2 blocks/CU overlap is preserved. K bits identical -> same numerics.
__global__ __launch_bounds__(512, 4) void k_attn(const u16* __restrict__ qg, const u16* __restrict__ kg,
                                                 const u16* __restrict__ vtg, u16* __restrict__ ao){
  __shared__ __align__(16) char smem[38912];
  float* Ob  = (float*)smem;               // [256 q][36]    (epilogue)
  u16*   ObT = (u16*)smem;                 // [256 q][72]    (epilogue)
  float* Lb  = (float*)(smem + 36864);     // [2][256]

  int t = threadIdx.x, lane = t & 63, w = t >> 6;
  int c16 = lane & 15, quad = lane >> 4;
  int qq = w & 3, kh = w >> 2;
  // XCD swizzle: all 16 q-blocks of one (b,h) on one XCD (K/V L2-resident).
  int wg = blockIdx.x + (blockIdx.y << 4) + (blockIdx.z << 8);  // 0..511
  int xcd = wg & 7, loc = wg >> 3;
  int nw = (xcd << 6) + loc;
  int q0 = (nw & 15) * 256;
  int hb = nw >> 4;
  int h = hb & 15, b = hb >> 4;
  size_t rowbase = (size_t)b * S_;
  const u16* vbase = vtg + ((size_t)h*64)*M_TOT + b*S_;   // V^T row stride M_TOT

  // V staging: thread t owns linear 16B chunks t and t+512 of the V tile;
  // global source chunk XOR-pre-swizzled so ds_reads can swizzle (rule #21).
  int vrow0 = t >> 4,         vsw0 = ((t & 15) ^ (vrow0 & 15));
  int vrow1 = (t + 512) >> 4, vsw1 = ((t & 15) ^ (vrow1 & 15));
  const u16* vgp0 = vbase + (size_t)vrow0*M_TOT + vsw0*8;
  const u16* vgp1 = vbase + (size_t)vrow1*M_TOT + vsw1*8;
  char* vd0 = smem + t*16;
  char* vd1 = smem + t*16 + 8192;

  auto stage = [&](int boff, int kv0){
    gld_lds16(vgp0 + kv0, vd0 + boff);
    gld_lds16(vgp1 + kv0, vd1 + boff);
  };

  // per-thread K base: row = rowbase + kh*64 + c16 (+ kv0 + mt*16), col = h*64 + quad*8 (+ ks*32)
  const u16* kgr = kg + (rowbase + kh*64 + c16)*DM + h*64 + quad*8;

  // persistent K frags for tile 0 (direct global; 4 qq-waves share rows -> L1 hits)
  s16x8 kf[4][2];
  #pragma unroll
  for (int mt=0;mt<4;mt++)
    #pragma unroll
    for (int ks=0;ks<2;ks++)
      kf[mt][ks] = *(const s16x8*)(kgr + (size_t)(mt*16)*DM + ks*32);

  stage(0, 0);   // prime V buffer 0

  // persistent Q B-frags (pre-scaled by CL2)
  s16x8 qf[4][2];
  #pragma unroll
  for (int nt=0;nt<4;nt++)
    #pragma unroll
    for (int ks=0;ks<2;ks++)
      qf[nt][ks] = *(const s16x8*)(qg + (rowbase + q0 + qq*64 + nt*16 + c16)*DM + h*64 + ks*32 + quad*8);

  // oacc[dt][nt]: O^T[d=dt*16+quad*4+r][q=qq*64+nt*16+c16], partial over kv-half kh
  f32x4 oacc[4][4] = {};
  float lacc[4] = {0.f,0.f,0.f,0.f};

  auto compute = [&](int boff, int kvn, bool pref){
    const u16* Vt = (const u16*)(smem + boff);    // [64 d][128 kv] swz

    // S^T tile: kv = kh*64 + mt*16 + quad*4 + r, q = qq*64 + nt*16 + c16
    f32x4 sc[4][4] = {};
    #pragma unroll
    for (int mt=0;mt<4;mt++){
      #pragma unroll
      for (int ks=0;ks<2;ks++){
        #pragma unroll
        for (int nt=0;nt<4;nt++)
          sc[mt][nt] = __builtin_amdgcn_mfma_f32_16x16x32_bf16(kf[mt][ks], qf[nt][ks], sc[mt][nt], 0,0,0);
      }
    }

    // prefetch next tile's K into the same regs (after last kf use; ~2000cy to land)
    if (pref){
      #pragma unroll
      for (int mt=0;mt<4;mt++)
        #pragma unroll
        for (int ks=0;ks<2;ks++)
          kf[mt][ks] = *(const s16x8*)(kgr + (size_t)(kvn + mt*16)*DM + ks*32);
    }

    // p = exp2(s); accumulate per-lane l; pack to bf16
    uint32_t pk[4][4][2];
    #pragma unroll
    for (int mt=0;mt<4;mt++){
      #pragma unroll
      for (int nt=0;nt<4;nt++){
        float p0 = __builtin_amdgcn_exp2f(sc[mt][nt][0]);
        float p1 = __builtin_amdgcn_exp2f(sc[mt][nt][1]);
        float p2 = __builtin_amdgcn_exp2f(sc[mt][nt][2]);
        float p3 = __builtin_amdgcn_exp2f(sc[mt][nt][3]);
        lacc[nt] += (p0 + p1) + (p2 + p3);
        pk[mt][nt][0] = pkbf(p0, p1);
        pk[mt][nt][1] = pkbf(p2, p3);
      }
    }

    // O^T += V^T P^T, K=32: mt-pair (2mp,2mp+1) packs into one MFMA32.
    #pragma unroll
    for (int mp=0;mp<2;mp++){
      int mtA = mp*2, mtB = mp*2+1;
      #pragma unroll
      for (int dt=0;dt<4;dt++){
        union { s16x4 h[2]; s16x8 v8; } vf;
        vf.h[0] = *(const s16x4*)&Vt[(dt*16 + c16)*128 + (((kh*8 + mtA*2 + (quad>>1)) ^ c16) * 8) + (quad & 1)*4];
        vf.h[1] = *(const s16x4*)&Vt[(dt*16 + c16)*128 + (((kh*8 + mtB*2 + (quad>>1)) ^ c16) * 8) + (quad & 1)*4];
        #pragma unroll
        for (int nt=0;nt<4;nt++){
          union { uint32_t u[4]; s16x8 v; } pp;
          pp.u[0] = pk[mtA][nt][0]; pp.u[1] = pk[mtA][nt][1];
          pp.u[2] = pk[mtB][nt][0]; pp.u[3] = pk[mtB][nt][1];
          oacc[dt][nt] = __builtin_amdgcn_mfma_f32_16x16x32_bf16(vf.v8, pp.v, oacc[dt][nt], 0,0,0);
        }
      }
    }
  };

  __builtin_amdgcn_sched_barrier(0);   // pin prologue loads before loop's stage

  #define NT (S_/128)
  #pragma unroll 1
  for (int kvt = 0; kvt < NT; ++kvt){
    if (kvt+1 < NT){
      stage(((kvt+1) & 1) * 16384, (kvt+1)*128);       // prefetch V(t+1)
      asm volatile("s_waitcnt vmcnt(2)" ::: "memory"); // drain V(t)+K(t); keep V(t+1)
    } else {
      asm volatile("s_waitcnt vmcnt(0)" ::: "memory");
    }
    __builtin_amdgcn_s_barrier();
    __builtin_amdgcn_sched_barrier(0);
    compute((kvt & 1) * 16384, (kvt+1)*128, kvt+1 < NT);
    __builtin_amdgcn_s_barrier();
    __builtin_amdgcn_sched_barrier(0);
  }

  // ---- epilogue: reduce l across quads, merge kv-halves, normalize, store ----
  float lw[4];
  #pragma unroll
  for (int nt=0;nt<4;nt++){
    float l = lacc[nt];
    l += __shfl_xor(l, 16);
    l += __shfl_xor(l, 32);
    lw[nt] = l;
  }
  __syncthreads();                               // phase-1 smem free
  if (quad == 0){
    #pragma unroll
    for (int nt=0;nt<4;nt++) Lb[kh*256 + qq*64 + nt*16 + c16] = lw[nt];
  }
  uint32_t pko[4][4][2];
  float invl[4];
  #pragma unroll
  for (int dh=0; dh<2; dh++){
    if (kh == 1){
      #pragma unroll
      for (int dt2=0;dt2<2;dt2++)
        #pragma unroll
        for (int nt=0;nt<4;nt++)
          *(f32x4*)&Ob[(qq*64 + nt*16 + c16)*36 + dt2*16 + quad*4] = oacc[dh*2+dt2][nt];
    }
    __syncthreads();
    if (kh == 0){
      if (dh == 0){
        #pragma unroll
        for (int nt=0;nt<4;nt++){
          int ql = qq*64 + nt*16 + c16;
          invl[nt] = 1.0f / (Lb[ql] + Lb[256 + ql]);
        }
      }
      #pragma unroll
      for (int dt2=0;dt2<2;dt2++)
        #pragma unroll
        for (int nt=0;nt<4;nt++){
          f32x4 p = *(const f32x4*)&Ob[(qq*64 + nt*16 + c16)*36 + dt2*16 + quad*4];
          f32x4 o = oacc[dh*2+dt2][nt] + p;
          pko[dh*2+dt2][nt][0] = pkbf(o[0]*invl[nt], o[1]*invl[nt]);
          pko[dh*2+dt2][nt][1] = pkbf(o[2]*invl[nt], o[3]*invl[nt]);
        }
    }
    __syncthreads();
  }
  if (kh == 0){
    #pragma unroll
    for (int dt=0;dt<4;dt++)
      #pragma unroll
      for (int nt=0;nt<4;nt++){
        u32x2 pr; pr.x = pko[dt][nt][0]; pr.y = pko[dt][nt][1];
        *(u32x2*)&ObT[(qq*64 + nt*16 + c16)*72 + dt*16 + quad*4] = pr;
      }
  }
  __syncthreads();
  #pragma unroll
  for (int i=0;i<4;i++){
    int idx = t + i*512;
    int qr = idx >> 3, qc = (idx & 7)*8;
    *(s16x8*)(ao + (rowbase + q0 + qr)*DM + h*64 + qc) = *(const s16x8*)&ObT[qr*72 + qc];
  }
}

extern "C" void kernel_launch(void* const* d_in, const int* in_sizes, int n_in,
                              void* d_out, int out_size, void* d_ws, size_t ws_size,
                              hipStream_t stream){
  const float* x  = (const float*)d_in[0];
  const float* Wq = (const float*)d_in[1];
  const float* bq = (const float*)d_in[2];
  const float* Wk = (const float*)d_in[3];
  const float* bk = (const float*)d_in[4];
  const float* Wv = (const float*)d_in[5];
  const float* bv = (const float*)d_in[6];
  const float* Wo = (const float*)d_in[7];
  const float* bo = (const float*)d_in[8];

  char* ws = (char*)d_ws;
  const size_t XB = (size_t)M_TOT*DM*2;          // 16 MiB per activation buffer
  const size_t WTB = (size_t)4*DM*DM*2;          // 8 MiB for 4 transposed weights
  u16* xb  = (u16*)(ws);
  u16* wt  = (u16*)(ws + XB);
  u16* qb  = (u16*)(ws + XB + WTB);
  u16* kb  = (u16*)(ws + XB + WTB + XB);
  u16* vtb = (u16*)(ws + XB + WTB + 2*XB);       // V^T [1024][8192] direct from GEMM
  u16* aob = (u16*)(ws + XB + WTB + 3*XB);

  k_prep<<<dim3(4096 + 1024), 256, 0, stream>>>(x, xb, Wq, Wk, Wv, Wo, wt);
  k_gemm_qkv<<<dim3(8, M_TOT/128, 3), 256, 0, stream>>>(xb, wt, bq, bk, bv, qb, kb, vtb);
  k_attn<<<dim3(S_/256, H_, B_), 512, 0, stream>>>(qb, kb, vtb, aob);
  k_gemm_out<<<dim3(8, M_TOT/128), 256, 0, stream>>>(aob, wt + (size_t)3*DM*DM, bo, (float*)d_out);
}

// Round 9
// 355.408 us; speedup vs baseline: 3.3462x; 3.3462x over previous
//
#include <hip/hip_runtime.h>
#include <hip/hip_bf16.h>
#include <stdint.h>

#define B_ 2
#define S_ 4096
#define DM 1024
#define H_ 16
#define HD 64
#define M_TOT (B_*S_)   // 8192

typedef unsigned short u16;
typedef short s16x8 __attribute__((ext_vector_type(8)));
typedef short s16x4 __attribute__((ext_vector_type(4)));
typedef float f32x4 __attribute__((ext_vector_type(4)));
typedef uint32_t u32x2 __attribute__((ext_vector_type(2)));

__device__ __forceinline__ u16 f2bf(float f){
  union { float fv; uint32_t u; } x; x.fv = f;
  uint32_t r = (x.u + 0x7fffu + ((x.u >> 16) & 1u)) >> 16;
  return (u16)r;
}

#if __has_builtin(__builtin_amdgcn_cvt_pk_bf16_f32)
typedef __bf16 bf16x2_t __attribute__((ext_vector_type(2)));
__device__ __forceinline__ uint32_t pkbf(float a, float b){
  union { bf16x2_t v; uint32_t u; } x;
  x.v = __builtin_amdgcn_cvt_pk_bf16_f32(a, b);
  return x.u;
}
#else
__device__ __forceinline__ uint32_t pkbf(float a, float b){
  union { float f; uint32_t u; } xa, xb; xa.f = a; xb.f = b;
  return __builtin_amdgcn_perm(xb.u + 0x8000u, xa.u + 0x8000u, 0x07060302u);
}
#endif

__device__ __forceinline__ void gld_lds16(const void* g, void* l){
  __builtin_amdgcn_global_load_lds((const __attribute__((address_space(1))) void*)g,
                                   (__attribute__((address_space(3))) void*)l, 16, 0, 0);
}

// ------- merged prep: x fp32->bf16 (blocks 0..4095) + W transpose (4096..5119) ----
__global__ __launch_bounds__(256) void k_prep(const float* __restrict__ x, u16* __restrict__ xb,
                                              const float* __restrict__ W0, const float* __restrict__ W1,
                                              const float* __restrict__ W2, const float* __restrict__ W3,
                                              u16* __restrict__ wt){
  __shared__ u16 T[64*66];
  int t = threadIdx.x;
  if (blockIdx.x < 4096){
    size_t i = (size_t)blockIdx.x * 256 + t;
    const float4* p = (const float4*)x + i*2;
    float4 a = p[0], b = p[1];
    union { u16 u[8]; uint4 v; } o;
    o.u[0]=f2bf(a.x); o.u[1]=f2bf(a.y); o.u[2]=f2bf(a.z); o.u[3]=f2bf(a.w);
    o.u[4]=f2bf(b.x); o.u[5]=f2bf(b.y); o.u[6]=f2bf(b.z); o.u[7]=f2bf(b.w);
    ((uint4*)xb)[i] = o.v;
    return;
  }
  int idx = blockIdx.x - 4096;           // 0..1023
  int bx = idx & 15, by = (idx >> 4) & 15, bz = idx >> 8;
  const float* W = bz==0?W0: bz==1?W1: bz==2?W2:W3;
  u16* out = wt + (size_t)bz * DM * DM;
  int n0 = bx*64, k0 = by*64;
  #pragma unroll
  for (int i=0;i<4;i++){
    int id2 = t + i*256;
    int kr = id2 >> 4, n4 = id2 & 15;
    float4 v = *(const float4*)(W + (size_t)(k0+kr)*DM + n0 + n4*4);
    T[(n4*4+0)*66 + kr] = f2bf(v.x);
    T[(n4*4+1)*66 + kr] = f2bf(v.y);
    T[(n4*4+2)*66 + kr] = f2bf(v.z);
    T[(n4*4+3)*66 + kr] = f2bf(v.w);
  }
  __syncthreads();
  #pragma unroll
  for (int i=0;i<2;i++){
    int id2 = t + i*256;
    int n = id2 >> 3, k8 = id2 & 7;
    union { u16 u[8]; uint4 v; } o;
    #pragma unroll
    for (int j=0;j<8;j++) o.u[j] = T[n*66 + k8*8 + j];
    *(uint4*)(out + (size_t)(n0+n)*DM + k0 + k8*8) = o.v;
  }
}

// ------------- 256x128 MFMA GEMM, A[M,K] bf16 row-major, BT[N,K] bf16 -------
// Round-9: BM 128 -> 256 with 512 threads (8 waves, 4M x 2N). Same proven
// single-buffer 2-barrier structure + XOR swizzle as round-5/7. Per-wave
// MFMA per barrier-pair doubles (16 -> 32); blocks per z halve (256, still
// 1/CU x 3z); A-staging bytes per output x0.75. LDS 48 KB (As 32 + Bs 16);
// bf16 epilogue restaged through LDS in two 32 KB half-tiles for b128 stores.
__device__ __forceinline__ void gemm256(const u16* __restrict__ A, const u16* __restrict__ BT,
                                        const float* __restrict__ bias, bool brow, float scale,
                                        u16* __restrict__ outb, float* __restrict__ outf,
                                        int m0, int n0, int ldo){
  __shared__ __align__(16) u16 S[24576];     // As = S[0:16384), Bs = S[16384:24576)
  u16* As = S;
  u16* Bs = S + 16384;
  int t = threadIdx.x;                        // 0..511
  int lane = t & 63, w = t >> 6;              // 8 waves
  int wr = w >> 1, wc = w & 1;                // 4M x 2N
  int c16 = lane & 15, quad = lane >> 4;
  f32x4 acc[4][4] = {};
  // staging: As 2048 chunks (4/thread), Bs 1024 chunks (2/thread).
  // chunk c: row = c>>3, col-chunk = (c&7) ^ (row&7) pre-swizzled at source.
  const u16* ap[4]; const u16* bp[2];
  #pragma unroll
  for (int i=0;i<4;i++){
    int c = t + i*512;
    int row = c >> 3, scol = (c & 7) ^ (row & 7);
    ap[i] = A + (size_t)(m0+row)*DM + scol*8;
  }
  #pragma unroll
  for (int i=0;i<2;i++){
    int c = t + i*512;
    int row = c >> 3, scol = (c & 7) ^ (row & 7);
    bp[i] = BT + (size_t)(n0+row)*DM + scol*8;
  }
  for (int k0 = 0; k0 < DM; k0 += 64){
    #pragma unroll
    for (int i=0;i<4;i++) gld_lds16(ap[i] + k0, &As[(t + i*512)*8]);
    #pragma unroll
    for (int i=0;i<2;i++) gld_lds16(bp[i] + k0, &Bs[(t + i*512)*8]);
    __syncthreads();
    #pragma unroll
    for (int ks=0; ks<2; ks++){
      s16x8 af[4], bfr[4];
      #pragma unroll
      for (int mi=0;mi<4;mi++){
        int row = wr*64 + mi*16 + c16;                       // 0..255
        af[mi] = *(const s16x8*)&As[row*64 + (((ks*4 + quad) ^ (row & 7))*8)];
      }
      #pragma unroll
      for (int ni=0;ni<4;ni++){
        int row = wc*64 + ni*16 + c16;                       // 0..127
        bfr[ni] = *(const s16x8*)&Bs[row*64 + (((ks*4 + quad) ^ (row & 7))*8)];
      }
      #pragma unroll
      for (int mi=0;mi<4;mi++)
        #pragma unroll
        for (int ni=0;ni<4;ni++)
          acc[mi][ni] = __builtin_amdgcn_mfma_f32_16x16x32_bf16(af[mi], bfr[ni], acc[mi][ni], 0, 0, 0);
    }
    __syncthreads();
  }
  if (outb){
    // bf16 epilogue: two 128-row halves staged through S (32 KB), b128 stores.
    #pragma unroll
    for (int hh=0; hh<2; hh++){
      if ((wr >> 1) == hh){
        #pragma unroll
        for (int mi=0;mi<4;mi++){
          #pragma unroll
          for (int ni=0;ni<4;ni++){
            int lc = wc*64 + ni*16 + c16;          // 0..127
            float bc = brow ? 0.0f : bias[n0 + lc];
            int chunk = lc >> 3, off = lc & 7;
            #pragma unroll
            for (int r=0;r<4;r++){
              int lrow = (wr & 1)*64 + mi*16 + quad*4 + r;   // 0..127 in half
              float bb = brow ? bias[m0 + hh*128 + lrow] : bc;
              float v = (acc[mi][ni][r] + bb) * scale;
              S[lrow*128 + ((chunk ^ (lrow & 7))<<3) + off] = f2bf(v);
            }
          }
        }
      }
      __syncthreads();
      #pragma unroll
      for (int i=0;i<4;i++){
        int c = t + i*512;                 // 0..2047
        int row = c >> 4, ch = c & 15;     // 128 rows x 16 chunks
        uint4 vv = *(const uint4*)&S[row*128 + ((ch ^ (row & 7))<<3) + 0];
        *(uint4*)(outb + (size_t)(m0 + hh*128 + row)*ldo + n0 + ch*8) = vv;
      }
      __syncthreads();
    }
  } else {
    // fp32: direct stores (64B/quad segments line-efficient).
    #pragma unroll
    for (int mi=0;mi<4;mi++){
      #pragma unroll
      for (int ni=0;ni<4;ni++){
        int col = n0 + wc*64 + ni*16 + c16;
        float bc = bias[col];
        #pragma unroll
        for (int r=0;r<4;r++){
          int row = m0 + wr*64 + mi*16 + quad*4 + r;
          outf[(size_t)row*ldo + col] = (acc[mi][ni][r] + bc) * scale;
        }
      }
    }
  }
}

#define CL2 0.18033688011112042f   // log2(e)/sqrt(64)

// XCD swizzle for the 32Mx8N tile grid (256 blocks, 256 % 8 == 0): XCD x
// owns a 4-M-tile band x all 8 N-tiles -> A panels (2MB) + W (2MB) L2-fit.
__device__ __forceinline__ void gemm_swz256(int wg, int& mt, int& nt){
  int xcd = wg & 7, loc = wg >> 3;   // loc 0..31
  mt = (xcd << 2) + (loc >> 3);      // 0..31
  nt = loc & 7;                      // 0..7
}

// z=0: Q = X*Wq (scaled CL2), z=1: K = X*Wk, z=2: V^T = Wv^T * X^T
// (roles swapped; tile grid re-mapped bijectively 32x8 -> 4x64).
__global__ __launch_bounds__(512) void k_gemm_qkv(const u16* __restrict__ xb, const u16* __restrict__ wt,
                                                  const float* __restrict__ b0, const float* __restrict__ b1,
                                                  const float* __restrict__ b2,
                                                  u16* __restrict__ q, u16* __restrict__ k, u16* __restrict__ vt){
  int z = blockIdx.z;
  int mt, nt;
  gemm_swz256(blockIdx.x + (blockIdx.y << 3), mt, nt);
  if (z == 2){
    int mV = (nt >> 1), nV = mt*2 + (nt & 1);        // 4 x 64 tiles
    gemm256(wt + 2*(size_t)DM*DM, xb, b2, true, 1.0f, vt, nullptr,
            mV*256, nV*128, M_TOT);
  } else {
    gemm256(xb, wt + (size_t)z*DM*DM, z ? b1 : b0, false, z ? 1.0f : CL2,
            z ? k : q, nullptr, mt*256, nt*128, DM);
  }
}

__global__ __launch_bounds__(512) void k_gemm_out(const u16* __restrict__ ab, const u16* __restrict__ wto,
                                                  const float* __restrict__ bias, float* __restrict__ out){
  int mt, nt;
  gemm_swz256(blockIdx.x + (blockIdx.y << 3), mt, nt);
  gemm256(ab, wto, bias, false, 1.0f, nullptr, out, mt*256, nt*128, DM);
}

// ---------------- flash attention: round-7 v13 verbatim (171.0 us) ---------
// K staged in LDS (XOR-swizzled), V^T stride M_TOT, PV via K=32 MFMA,
// dbuf gld_lds + counted vmcnt(4), launch_bounds(512,2). Do not touch:
// five orthogonal interventions all left it at 171 +- 1 us.
__global__ __launch_bounds__(512, 2) void k_attn(const u16* __restrict__ qg, const u16* __restrict__ kg,
                                                 const u16* __restrict__ vtg, u16* __restrict__ ao){
  __shared__ __align__(16) char smem[67584];
  float* Ob  = (float*)smem;               // [256 q][36]    (epilogue)
  u16*   ObT = (u16*)smem;                 // [256 q][72]    (epilogue)
  float* Lb  = (float*)(smem + 65536);     // [2][256]

  int t = threadIdx.x, lane = t & 63, w = t >> 6;
  int c16 = lane & 15, quad = lane >> 4;
  int qq = w & 3, kh = w >> 2;
  int wg = blockIdx.x + (blockIdx.y << 4) + (blockIdx.z << 8);  // 0..511
  int xcd = wg & 7, loc = wg >> 3;
  int nw = (xcd << 6) + loc;
  int q0 = (nw & 15) * 256;
  int hb = nw >> 4;
  int h = hb & 15, b = hb >> 4;
  size_t rowbase = (size_t)b * S_;
  const u16* vbase = vtg + ((size_t)h*64)*M_TOT + b*S_;   // V^T row stride M_TOT

  int krow0 = t >> 3,         ksw0 = ((t & 7) ^ (krow0 & 7));
  int krow1 = (t + 512) >> 3, ksw1 = ((t & 7) ^ (krow1 & 7));
  const u16* kgp0 = kg + (rowbase + krow0)*DM + h*64 + ksw0*8;
  const u16* kgp1 = kg + (rowbase + krow1)*DM + h*64 + ksw1*8;
  int vrow0 = t >> 4,         vsw0 = ((t & 15) ^ (vrow0 & 15));
  int vrow1 = (t + 512) >> 4, vsw1 = ((t & 15) ^ (vrow1 & 15));
  const u16* vgp0 = vbase + (size_t)vrow0*M_TOT + vsw0*8;
  const u16* vgp1 = vbase + (size_t)vrow1*M_TOT + vsw1*8;
  char* kd0 = smem + t*16;
  char* kd1 = smem + t*16 + 8192;
  char* vd0 = smem + 16384 + t*16;
  char* vd1 = smem + 16384 + t*16 + 8192;

  auto stage = [&](int boff, int kv0){
    size_t ko = (size_t)kv0 * DM;
    gld_lds16(kgp0 + ko, kd0 + boff);
    gld_lds16(kgp1 + ko, kd1 + boff);
    gld_lds16(vgp0 + kv0, vd0 + boff);
    gld_lds16(vgp1 + kv0, vd1 + boff);
  };

  stage(0, 0);

  s16x8 qf[4][2];
  #pragma unroll
  for (int nt=0;nt<4;nt++)
    #pragma unroll
    for (int ks=0;ks<2;ks++)
      qf[nt][ks] = *(const s16x8*)(qg + (rowbase + q0 + qq*64 + nt*16 + c16)*DM + h*64 + ks*32 + quad*8);

  f32x4 oacc[4][4] = {};
  float lacc[4] = {0.f,0.f,0.f,0.f};

  auto compute = [&](int boff){
    const u16* Kt = (const u16*)(smem + boff);            // [128 kv][64 d] swz
    const u16* Vt = (const u16*)(smem + boff + 16384);    // [64 d][128 kv] swz

    f32x4 sc[4][4] = {};
    #pragma unroll
    for (int mt=0;mt<4;mt++){
      #pragma unroll
      for (int ks=0;ks<2;ks++){
        s16x8 kf = *(const s16x8*)&Kt[(kh*64 + mt*16 + c16)*64 + (((ks*4 + quad) ^ (c16 & 7)) * 8)];
        #pragma unroll
        for (int nt=0;nt<4;nt++)
          sc[mt][nt] = __builtin_amdgcn_mfma_f32_16x16x32_bf16(kf, qf[nt][ks], sc[mt][nt], 0,0,0);
      }
    }

    uint32_t pk[4][4][2];
    #pragma unroll
    for (int mt=0;mt<4;mt++){
      #pragma unroll
      for (int nt=0;nt<4;nt++){
        float p0 = __builtin_amdgcn_exp2f(sc[mt][nt][0]);
        float p1 = __builtin_amdgcn_exp2f(sc[mt][nt][1]);
        float p2 = __builtin_amdgcn_exp2f(sc[mt][nt][2]);
        float p3 = __builtin_amdgcn_exp2f(sc[mt][nt][3]);
        lacc[nt] += (p0 + p1) + (p2 + p3);
        pk[mt][nt][0] = pkbf(p0, p1);
        pk[mt][nt][1] = pkbf(p2, p3);
      }
    }

    #pragma unroll
    for (int mp=0;mp<2;mp++){
      int mtA = mp*2, mtB = mp*2+1;
      #pragma unroll
      for (int dt=0;dt<4;dt++){
        union { s16x4 h[2]; s16x8 v8; } vf;
        vf.h[0] = *(const s16x4*)&Vt[(dt*16 + c16)*128 + (((kh*8 + mtA*2 + (quad>>1)) ^ c16) * 8) + (quad & 1)*4];
        vf.h[1] = *(const s16x4*)&Vt[(dt*16 + c16)*128 + (((kh*8 + mtB*2 + (quad>>1)) ^ c16) * 8) + (quad & 1)*4];
        #pragma unroll
        for (int nt=0;nt<4;nt++){
          union { uint32_t u[4]; s16x8 v; } pp;
          pp.u[0] = pk[mtA][nt][0]; pp.u[1] = pk[mtA][nt][1];
          pp.u[2] = pk[mtB][nt][0]; pp.u[3] = pk[mtB][nt][1];
          oacc[dt][nt] = __builtin_amdgcn_mfma_f32_16x16x32_bf16(vf.v8, pp.v, oacc[dt][nt], 0,0,0);
        }
      }
    }
  };

  #define NT (S_/128)
  #pragma unroll 1
  for (int kvt = 0; kvt < NT-1; ++kvt){
    stage(((kvt+1) & 1) * 32768, (kvt+1)*128);           // prefetch tile t+1
    asm volatile("s_waitcnt vmcnt(4)" ::: "memory");     // tile t landed
    __builtin_amdgcn_s_barrier();
    __builtin_amdgcn_sched_barrier(0);
    compute((kvt & 1) * 32768);
    __builtin_amdgcn_s_barrier();
    __builtin_amdgcn_sched_barrier(0);
  }
  asm volatile("s_waitcnt vmcnt(0)" ::: "memory");
  __builtin_amdgcn_s_barrier();
  __builtin_amdgcn_sched_barrier(0);
  compute(((NT-1) & 1) * 32768);

  float lw[4];
  #pragma unroll
  for (int nt=0;nt<4;nt++){
    float l = lacc[nt];
    l += __shfl_xor(l, 16);
    l += __shfl_xor(l, 32);
    lw[nt] = l;
  }
  __syncthreads();
  if (quad == 0){
    #pragma unroll
    for (int nt=0;nt<4;nt++) Lb[kh*256 + qq*64 + nt*16 + c16] = lw[nt];
  }
  uint32_t pko[4][4][2];
  float invl[4];
  #pragma unroll
  for (int dh=0; dh<2; dh++){
    if (kh == 1){
      #pragma unroll
      for (int dt2=0;dt2<2;dt2++)
        #pragma unroll
        for (int nt=0;nt<4;nt++)
          *(f32x4*)&Ob[(qq*64 + nt*16 + c16)*36 + dt2*16 + quad*4] = oacc[dh*2+dt2][nt];
    }
    __syncthreads();
    if (kh == 0){
      if (dh == 0){
        #pragma unroll
        for (int nt=0;nt<4;nt++){
          int ql = qq*64 + nt*16 + c16;
          invl[nt] = 1.0f / (Lb[ql] + Lb[256 + ql]);
        }
      }
      #pragma unroll
      for (int dt2=0;dt2<2;dt2++)
        #pragma unroll
        for (int nt=0;nt<4;nt++){
          f32x4 p = *(const f32x4*)&Ob[(qq*64 + nt*16 + c16)*36 + dt2*16 + quad*4];
          f32x4 o = oacc[dh*2+dt2][nt] + p;
          pko[dh*2+dt2][nt][0] = pkbf(o[0]*invl[nt], o[1]*invl[nt]);
          pko[dh*2+dt2][nt][1] = pkbf(o[2]*invl[nt], o[3]*invl[nt]);
        }
    }
    __syncthreads();
  }
  if (kh == 0){
    #pragma unroll
    for (int dt=0;dt<4;dt++)
      #pragma unroll
      for (int nt=0;nt<4;nt++){
        u32x2 pr; pr.x = pko[dt][nt][0]; pr.y = pko[dt][nt][1];
        *(u32x2*)&ObT[(qq*64 + nt*16 + c16)*72 + dt*16 + quad*4] = pr;
      }
  }
  __syncthreads();
  #pragma unroll
  for (int i=0;i<4;i++){
    int idx = t + i*512;
    int qr = idx >> 3, qc = (idx & 7)*8;
    *(s16x8*)(ao + (rowbase + q0 + qr)*DM + h*64 + qc) = *(const s16x8*)&ObT[qr*72 + qc];
  }
}

extern "C" void kernel_launch(void* const* d_in, const int* in_sizes, int n_in,
                              void* d_out, int out_size, void* d_ws, size_t ws_size,
                              hipStream_t stream){
  const float* x  = (const float*)d_in[0];
  const float* Wq = (const float*)d_in[1];
  const float* bq = (const float*)d_in[2];
  const float* Wk = (const float*)d_in[3];
  const float* bk = (const float*)d_in[4];
  const float* Wv = (const float*)d_in[5];
  const float* bv = (const float*)d_in[6];
  const float* Wo = (const float*)d_in[7];
  const float* bo = (const float*)d_in[8];

  char* ws = (char*)d_ws;
  const size_t XB = (size_t)M_TOT*DM*2;          // 16 MiB per activation buffer
  const size_t WTB = (size_t)4*DM*DM*2;          // 8 MiB for 4 transposed weights
  u16* xb  = (u16*)(ws);
  u16* wt  = (u16*)(ws + XB);
  u16* qb  = (u16*)(ws + XB + WTB);
  u16* kb  = (u16*)(ws + XB + WTB + XB);
  u16* vtb = (u16*)(ws + XB + WTB + 2*XB);       // V^T [1024][8192] direct from GEMM
  u16* aob = (u16*)(ws + XB + WTB + 3*XB);

  k_prep<<<dim3(4096 + 1024), 256, 0, stream>>>(x, xb, Wq, Wk, Wv, Wo, wt);
  k_gemm_qkv<<<dim3(8, 32, 3), 512, 0, stream>>>(xb, wt, bq, bk, bv, qb, kb, vtb);
  k_attn<<<dim3(S_/256, H_, B_), 512, 0, stream>>>(qb, kb, vtb, aob);
  k_gemm_out<<<dim3(8, 32), 512, 0, stream>>>(aob, wt + (size_t)3*DM*DM, bo, (float*)d_out);
}

// Round 10
// 338.980 us; speedup vs baseline: 3.5084x; 1.0485x over previous
//
#include <hip/hip_runtime.h>
#include <hip/hip_bf16.h>
#include <stdint.h>

#define B_ 2
#define S_ 4096
#define DM 1024
#define H_ 16
#define HD 64
#define M_TOT (B_*S_)   // 8192

typedef unsigned short u16;
typedef short s16x8 __attribute__((ext_vector_type(8)));
typedef short s16x4 __attribute__((ext_vector_type(4)));
typedef float f32x4 __attribute__((ext_vector_type(4)));
typedef uint32_t u32x2 __attribute__((ext_vector_type(2)));

__device__ __forceinline__ u16 f2bf(float f){
  union { float fv; uint32_t u; } x; x.fv = f;
  uint32_t r = (x.u + 0x7fffu + ((x.u >> 16) & 1u)) >> 16;
  return (u16)r;
}

#if __has_builtin(__builtin_amdgcn_cvt_pk_bf16_f32)
typedef __bf16 bf16x2_t __attribute__((ext_vector_type(2)));
__device__ __forceinline__ uint32_t pkbf(float a, float b){
  union { bf16x2_t v; uint32_t u; } x;
  x.v = __builtin_amdgcn_cvt_pk_bf16_f32(a, b);
  return x.u;
}
#else
__device__ __forceinline__ uint32_t pkbf(float a, float b){
  union { float f; uint32_t u; } xa, xb; xa.f = a; xb.f = b;
  return __builtin_amdgcn_perm(xb.u + 0x8000u, xa.u + 0x8000u, 0x07060302u);
}
#endif

__device__ __forceinline__ void gld_lds16(const void* g, void* l){
  __builtin_amdgcn_global_load_lds((const __attribute__((address_space(1))) void*)g,
                                   (__attribute__((address_space(3))) void*)l, 16, 0, 0);
}

// ------- merged prep: x fp32->bf16 (blocks 0..4095) + W transpose (4096..5119) ----
__global__ __launch_bounds__(256) void k_prep(const float* __restrict__ x, u16* __restrict__ xb,
                                              const float* __restrict__ W0, const float* __restrict__ W1,
                                              const float* __restrict__ W2, const float* __restrict__ W3,
                                              u16* __restrict__ wt){
  __shared__ u16 T[64*66];
  int t = threadIdx.x;
  if (blockIdx.x < 4096){
    size_t i = (size_t)blockIdx.x * 256 + t;
    const float4* p = (const float4*)x + i*2;
    float4 a = p[0], b = p[1];
    union { u16 u[8]; uint4 v; } o;
    o.u[0]=f2bf(a.x); o.u[1]=f2bf(a.y); o.u[2]=f2bf(a.z); o.u[3]=f2bf(a.w);
    o.u[4]=f2bf(b.x); o.u[5]=f2bf(b.y); o.u[6]=f2bf(b.z); o.u[7]=f2bf(b.w);
    ((uint4*)xb)[i] = o.v;
    return;
  }
  int idx = blockIdx.x - 4096;           // 0..1023
  int bx = idx & 15, by = (idx >> 4) & 15, bz = idx >> 8;
  const float* W = bz==0?W0: bz==1?W1: bz==2?W2:W3;
  u16* out = wt + (size_t)bz * DM * DM;
  int n0 = bx*64, k0 = by*64;
  #pragma unroll
  for (int i=0;i<4;i++){
    int id2 = t + i*256;
    int kr = id2 >> 4, n4 = id2 & 15;
    float4 v = *(const float4*)(W + (size_t)(k0+kr)*DM + n0 + n4*4);
    T[(n4*4+0)*66 + kr] = f2bf(v.x);
    T[(n4*4+1)*66 + kr] = f2bf(v.y);
    T[(n4*4+2)*66 + kr] = f2bf(v.z);
    T[(n4*4+3)*66 + kr] = f2bf(v.w);
  }
  __syncthreads();
  #pragma unroll
  for (int i=0;i<2;i++){
    int id2 = t + i*256;
    int n = id2 >> 3, k8 = id2 & 7;
    union { u16 u[8]; uint4 v; } o;
    #pragma unroll
    for (int j=0;j<8;j++) o.u[j] = T[n*66 + k8*8 + j];
    *(uint4*)(out + (size_t)(n0+n)*DM + k0 + k8*8) = o.v;
  }
}

// ---------------- 128x128 MFMA GEMM, A[M,K] bf16 row-major, BT[N,K] bf16 ----
// Round-10: BACK to the round-2/round-4 BK=32 / 16 KB-LDS body — the fastest
// GEMM measured this session (rest 172 incl. k_vt). Cross-round ledger:
// rest-time tracks LDS footprint (16KB:172 < 32KB:175-178 < 48KB:181 <
// dbuf:188) -> occupancy-driven TLP is the latency hider for this small-K
// GEMM; every scheduling trick was neutral or worse. Only delta vs r4:
// brow/ldo epilogue params (r6-proven semantics) so z=2 emits V^T directly
// and k_vt stays deleted.
__device__ __forceinline__ void gemm128(const u16* __restrict__ A, const u16* __restrict__ BT,
                                        const float* __restrict__ bias, bool brow, float scale,
                                        u16* __restrict__ outb, float* __restrict__ outf,
                                        int m0, int n0, int ldo){
  __shared__ __align__(16) u16 As[128*32];
  __shared__ __align__(16) u16 Bs[128*32];
  int t = threadIdx.x;
  int lane = t & 63, w = t >> 6;
  int wm = w & 1, wn = w >> 1;
  int c16 = lane & 15, quad = lane >> 4;
  f32x4 acc[4][4] = {};
  for (int k0 = 0; k0 < DM; k0 += 32){
    #pragma unroll
    for (int i=0;i<2;i++){
      int idx = t + i*256;
      int row = idx >> 2, c8 = (idx & 3) << 3;
      gld_lds16(A  + (size_t)(m0+row)*DM + k0 + c8, &As[idx*8]);
      gld_lds16(BT + (size_t)(n0+row)*DM + k0 + c8, &Bs[idx*8]);
    }
    __syncthreads();
    s16x8 af[4], bf[4];
    #pragma unroll
    for (int mi=0;mi<4;mi++) af[mi] = *(const s16x8*)&As[(wm*64+mi*16+c16)*32 + quad*8];
    #pragma unroll
    for (int ni=0;ni<4;ni++) bf[ni] = *(const s16x8*)&Bs[(wn*64+ni*16+c16)*32 + quad*8];
    #pragma unroll
    for (int mi=0;mi<4;mi++)
      #pragma unroll
      for (int ni=0;ni<4;ni++)
        acc[mi][ni] = __builtin_amdgcn_mfma_f32_16x16x32_bf16(af[mi], bf[ni], acc[mi][ni], 0, 0, 0);
    __syncthreads();
  }
  #pragma unroll
  for (int mi=0;mi<4;mi++){
    #pragma unroll
    for (int ni=0;ni<4;ni++){
      int col = n0 + wn*64 + ni*16 + c16;
      float bc = brow ? 0.0f : bias[col];
      #pragma unroll
      for (int r=0;r<4;r++){
        int row = m0 + wm*64 + mi*16 + quad*4 + r;
        float bb = brow ? bias[row] : bc;
        float v = (acc[mi][ni][r] + bb) * scale;
        if (outb) outb[(size_t)row*ldo + col] = f2bf(v);
        else      outf[(size_t)row*ldo + col] = v;
      }
    }
  }
}

#define CL2 0.18033688011112042f   // log2(e)/sqrt(64)

// T1 XCD-aware swizzle (r4-proven, -12 us): XCD x owns M-tile band
// [x*8, x*8+8) x all 8 N-tiles -> A-panels + weight fit its 4 MB L2.
// Bijective (512 % 8 == 0).
__device__ __forceinline__ void gemm_swz(int wg, int& m0, int& n0){
  int xcd = wg & 7, loc = wg >> 3;            // loc in [0,64)
  m0 = ((xcd << 3) + (loc >> 3)) * 128;       // M-tile 0..63
  n0 = (loc & 7) * 128;                       // N-tile 0..7
}

// z=0: Q = X*Wq (scaled CL2), z=1: K = X*Wk, z=2: V^T = Wv^T * X^T
// (roles swapped -> output [1024][8192], bias by row; k_vt stays deleted).
__global__ __launch_bounds__(256) void k_gemm_qkv(const u16* __restrict__ xb, const u16* __restrict__ wt,
                                                  const float* __restrict__ b0, const float* __restrict__ b1,
                                                  const float* __restrict__ b2,
                                                  u16* __restrict__ q, u16* __restrict__ k, u16* __restrict__ vt){
  int z = blockIdx.z;
  int m0, n0;
  gemm_swz(blockIdx.x + (blockIdx.y << 3), m0, n0);
  if (z == 2){
    gemm128(wt + 2*(size_t)DM*DM, xb, b2, true, 1.0f, vt, nullptr,
            n0, m0, M_TOT);                    // m in [0,1024), n in [0,8192)
  } else {
    gemm128(xb, wt + (size_t)z*DM*DM, z ? b1 : b0, false, z ? 1.0f : CL2,
            z ? k : q, nullptr, m0, n0, DM);
  }
}

__global__ __launch_bounds__(256) void k_gemm_out(const u16* __restrict__ ab, const u16* __restrict__ wto,
                                                  const float* __restrict__ bias, float* __restrict__ out){
  int m0, n0;
  gemm_swz(blockIdx.x + (blockIdx.y << 3), m0, n0);
  gemm128(ab, wto, bias, false, 1.0f, nullptr, out, m0, n0, DM);
}

// ---------------- flash attention: round-7 kernel verbatim (171.0 us) ------
// K staged in LDS (XOR-swizzled), V^T stride M_TOT, PV via K=32 MFMA,
// dbuf gld_lds + counted vmcnt(4), launch_bounds(512,2). Pinned at 171+-2
// across six interventions — do not touch.
__global__ __launch_bounds__(512, 2) void k_attn(const u16* __restrict__ qg, const u16* __restrict__ kg,
                                                 const u16* __restrict__ vtg, u16* __restrict__ ao){
  __shared__ __align__(16) char smem[67584];
  float* Ob  = (float*)smem;               // [256 q][36]    (epilogue)
  u16*   ObT = (u16*)smem;                 // [256 q][72]    (epilogue)
  float* Lb  = (float*)(smem + 65536);     // [2][256]

  int t = threadIdx.x, lane = t & 63, w = t >> 6;
  int c16 = lane & 15, quad = lane >> 4;
  int qq = w & 3, kh = w >> 2;
  int wg = blockIdx.x + (blockIdx.y << 4) + (blockIdx.z << 8);  // 0..511
  int xcd = wg & 7, loc = wg >> 3;
  int nw = (xcd << 6) + loc;
  int q0 = (nw & 15) * 256;
  int hb = nw >> 4;
  int h = hb & 15, b = hb >> 4;
  size_t rowbase = (size_t)b * S_;
  const u16* vbase = vtg + ((size_t)h*64)*M_TOT + b*S_;   // V^T row stride M_TOT

  int krow0 = t >> 3,         ksw0 = ((t & 7) ^ (krow0 & 7));
  int krow1 = (t + 512) >> 3, ksw1 = ((t & 7) ^ (krow1 & 7));
  const u16* kgp0 = kg + (rowbase + krow0)*DM + h*64 + ksw0*8;
  const u16* kgp1 = kg + (rowbase + krow1)*DM + h*64 + ksw1*8;
  int vrow0 = t >> 4,         vsw0 = ((t & 15) ^ (vrow0 & 15));
  int vrow1 = (t + 512) >> 4, vsw1 = ((t & 15) ^ (vrow1 & 15));
  const u16* vgp0 = vbase + (size_t)vrow0*M_TOT + vsw0*8;
  const u16* vgp1 = vbase + (size_t)vrow1*M_TOT + vsw1*8;
  char* kd0 = smem + t*16;
  char* kd1 = smem + t*16 + 8192;
  char* vd0 = smem + 16384 + t*16;
  char* vd1 = smem + 16384 + t*16 + 8192;

  auto stage = [&](int boff, int kv0){
    size_t ko = (size_t)kv0 * DM;
    gld_lds16(kgp0 + ko, kd0 + boff);
    gld_lds16(kgp1 + ko, kd1 + boff);
    gld_lds16(vgp0 + kv0, vd0 + boff);
    gld_lds16(vgp1 + kv0, vd1 + boff);
  };

  stage(0, 0);

  s16x8 qf[4][2];
  #pragma unroll
  for (int nt=0;nt<4;nt++)
    #pragma unroll
    for (int ks=0;ks<2;ks++)
      qf[nt][ks] = *(const s16x8*)(qg + (rowbase + q0 + qq*64 + nt*16 + c16)*DM + h*64 + ks*32 + quad*8);

  f32x4 oacc[4][4] = {};
  float lacc[4] = {0.f,0.f,0.f,0.f};

  auto compute = [&](int boff){
    const u16* Kt = (const u16*)(smem + boff);            // [128 kv][64 d] swz
    const u16* Vt = (const u16*)(smem + boff + 16384);    // [64 d][128 kv] swz

    f32x4 sc[4][4] = {};
    #pragma unroll
    for (int mt=0;mt<4;mt++){
      #pragma unroll
      for (int ks=0;ks<2;ks++){
        s16x8 kf = *(const s16x8*)&Kt[(kh*64 + mt*16 + c16)*64 + (((ks*4 + quad) ^ (c16 & 7)) * 8)];
        #pragma unroll
        for (int nt=0;nt<4;nt++)
          sc[mt][nt] = __builtin_amdgcn_mfma_f32_16x16x32_bf16(kf, qf[nt][ks], sc[mt][nt], 0,0,0);
      }
    }

    uint32_t pk[4][4][2];
    #pragma unroll
    for (int mt=0;mt<4;mt++){
      #pragma unroll
      for (int nt=0;nt<4;nt++){
        float p0 = __builtin_amdgcn_exp2f(sc[mt][nt][0]);
        float p1 = __builtin_amdgcn_exp2f(sc[mt][nt][1]);
        float p2 = __builtin_amdgcn_exp2f(sc[mt][nt][2]);
        float p3 = __builtin_amdgcn_exp2f(sc[mt][nt][3]);
        lacc[nt] += (p0 + p1) + (p2 + p3);
        pk[mt][nt][0] = pkbf(p0, p1);
        pk[mt][nt][1] = pkbf(p2, p3);
      }
    }

    #pragma unroll
    for (int mp=0;mp<2;mp++){
      int mtA = mp*2, mtB = mp*2+1;
      #pragma unroll
      for (int dt=0;dt<4;dt++){
        union { s16x4 h[2]; s16x8 v8; } vf;
        vf.h[0] = *(const s16x4*)&Vt[(dt*16 + c16)*128 + (((kh*8 + mtA*2 + (quad>>1)) ^ c16) * 8) + (quad & 1)*4];
        vf.h[1] = *(const s16x4*)&Vt[(dt*16 + c16)*128 + (((kh*8 + mtB*2 + (quad>>1)) ^ c16) * 8) + (quad & 1)*4];
        #pragma unroll
        for (int nt=0;nt<4;nt++){
          union { uint32_t u[4]; s16x8 v; } pp;
          pp.u[0] = pk[mtA][nt][0]; pp.u[1] = pk[mtA][nt][1];
          pp.u[2] = pk[mtB][nt][0]; pp.u[3] = pk[mtB][nt][1];
          oacc[dt][nt] = __builtin_amdgcn_mfma_f32_16x16x32_bf16(vf.v8, pp.v, oacc[dt][nt], 0,0,0);
        }
      }
    }
  };

  #define NT (S_/128)
  #pragma unroll 1
  for (int kvt = 0; kvt < NT-1; ++kvt){
    stage(((kvt+1) & 1) * 32768, (kvt+1)*128);           // prefetch tile t+1
    asm volatile("s_waitcnt vmcnt(4)" ::: "memory");     // tile t landed
    __builtin_amdgcn_s_barrier();
    __builtin_amdgcn_sched_barrier(0);
    compute((kvt & 1) * 32768);
    __builtin_amdgcn_s_barrier();
    __builtin_amdgcn_sched_barrier(0);
  }
  asm volatile("s_waitcnt vmcnt(0)" ::: "memory");
  __builtin_amdgcn_s_barrier();
  __builtin_amdgcn_sched_barrier(0);
  compute(((NT-1) & 1) * 32768);

  float lw[4];
  #pragma unroll
  for (int nt=0;nt<4;nt++){
    float l = lacc[nt];
    l += __shfl_xor(l, 16);
    l += __shfl_xor(l, 32);
    lw[nt] = l;
  }
  __syncthreads();
  if (quad == 0){
    #pragma unroll
    for (int nt=0;nt<4;nt++) Lb[kh*256 + qq*64 + nt*16 + c16] = lw[nt];
  }
  uint32_t pko[4][4][2];
  float invl[4];
  #pragma unroll
  for (int dh=0; dh<2; dh++){
    if (kh == 1){
      #pragma unroll
      for (int dt2=0;dt2<2;dt2++)
        #pragma unroll
        for (int nt=0;nt<4;nt++)
          *(f32x4*)&Ob[(qq*64 + nt*16 + c16)*36 + dt2*16 + quad*4] = oacc[dh*2+dt2][nt];
    }
    __syncthreads();
    if (kh == 0){
      if (dh == 0){
        #pragma unroll
        for (int nt=0;nt<4;nt++){
          int ql = qq*64 + nt*16 + c16;
          invl[nt] = 1.0f / (Lb[ql] + Lb[256 + ql]);
        }
      }
      #pragma unroll
      for (int dt2=0;dt2<2;dt2++)
        #pragma unroll
        for (int nt=0;nt<4;nt++){
          f32x4 p = *(const f32x4*)&Ob[(qq*64 + nt*16 + c16)*36 + dt2*16 + quad*4];
          f32x4 o = oacc[dh*2+dt2][nt] + p;
          pko[dh*2+dt2][nt][0] = pkbf(o[0]*invl[nt], o[1]*invl[nt]);
          pko[dh*2+dt2][nt][1] = pkbf(o[2]*invl[nt], o[3]*invl[nt]);
        }
    }
    __syncthreads();
  }
  if (kh == 0){
    #pragma unroll
    for (int dt=0;dt<4;dt++)
      #pragma unroll
      for (int nt=0;nt<4;nt++){
        u32x2 pr; pr.x = pko[dt][nt][0]; pr.y = pko[dt][nt][1];
        *(u32x2*)&ObT[(qq*64 + nt*16 + c16)*72 + dt*16 + quad*4] = pr;
      }
  }
  __syncthreads();
  #pragma unroll
  for (int i=0;i<4;i++){
    int idx = t + i*512;
    int qr = idx >> 3, qc = (idx & 7)*8;
    *(s16x8*)(ao + (rowbase + q0 + qr)*DM + h*64 + qc) = *(const s16x8*)&ObT[qr*72 + qc];
  }
}

extern "C" void kernel_launch(void* const* d_in, const int* in_sizes, int n_in,
                              void* d_out, int out_size, void* d_ws, size_t ws_size,
                              hipStream_t stream){
  const float* x  = (const float*)d_in[0];
  const float* Wq = (const float*)d_in[1];
  const float* bq = (const float*)d_in[2];
  const float* Wk = (const float*)d_in[3];
  const float* bk = (const float*)d_in[4];
  const float* Wv = (const float*)d_in[5];
  const float* bv = (const float*)d_in[6];
  const float* Wo = (const float*)d_in[7];
  const float* bo = (const float*)d_in[8];

  char* ws = (char*)d_ws;
  const size_t XB = (size_t)M_TOT*DM*2;          // 16 MiB per activation buffer
  const size_t WTB = (size_t)4*DM*DM*2;          // 8 MiB for 4 transposed weights
  u16* xb  = (u16*)(ws);
  u16* wt  = (u16*)(ws + XB);
  u16* qb  = (u16*)(ws + XB + WTB);
  u16* kb  = (u16*)(ws + XB + WTB + XB);
  u16* vtb = (u16*)(ws + XB + WTB + 2*XB);       // V^T [1024][8192] direct from GEMM
  u16* aob = (u16*)(ws + XB + WTB + 3*XB);

  k_prep<<<dim3(4096 + 1024), 256, 0, stream>>>(x, xb, Wq, Wk, Wv, Wo, wt);
  k_gemm_qkv<<<dim3(8, M_TOT/128, 3), 256, 0, stream>>>(xb, wt, bq, bk, bv, qb, kb, vtb);
  k_attn<<<dim3(S_/256, H_, B_), 512, 0, stream>>>(qb, kb, vtb, aob);
  k_gemm_out<<<dim3(8, M_TOT/128), 256, 0, stream>>>(aob, wt + (size_t)3*DM*DM, bo, (float*)d_out);
}